// Round 4
// baseline (473.638 us; speedup 1.0000x reference)
//
#include <hip/hip_runtime.h>

#define N_NODES  50000
#define N_EDGES  1600000
#define NODE_DIM 1024
#define HID      128
#define LN_EPS   1e-5f
#define NBUCK    196              // dst>>8 buckets (256 nodes each)
#define SHARD    6250             // N_EDGES / 256

typedef float f32x4 __attribute__((ext_vector_type(4)));
typedef __bf16 bf16x8 __attribute__((ext_vector_type(8)));
typedef unsigned short u16x8 __attribute__((ext_vector_type(8)));
typedef unsigned int u32x4 __attribute__((ext_vector_type(4)));

// HW bf16 convert: gfx950 lowers fptrunc f32->bf16 to v_cvt_pk_bf16_f32 (RNE)
__device__ __forceinline__ unsigned short f2bf(float f) {
  __bf16 b = (__bf16)f;
  return __builtin_bit_cast(unsigned short, b);
}
__device__ __forceinline__ unsigned int pkbf(float a, float b) {
  return (unsigned int)f2bf(a) | ((unsigned int)f2bf(b) << 16);
}
__device__ __forceinline__ float bf2f(unsigned short v) {
  return __uint_as_float((unsigned int)v << 16);
}

__device__ __forceinline__ int scan256_excl(int v, int buf[2][256], int t) {
  int cur = 0;
  buf[0][t] = v;
  __syncthreads();
  for (int off = 1; off < 256; off <<= 1) {
    int nxt = cur ^ 1;
    int s = buf[cur][t];
    if (t >= off) s += buf[cur][t - off];
    buf[nxt][t] = s;
    cur = nxt;
    __syncthreads();
  }
  return buf[cur][t] - v;
}

// ---------------------------------------------------------------------------
// K0: weight convert+PACK: pw f32 [HID][1024] -> bf16 fragment-ordered:
//   wp[ ((ks*8 + n)*64 + lane) * 8 + j ] = pw[n*16 + (lane&15)][ks*32 + (lane>>4)*8 + j]
// so a wave's B-fragment read in k_proj is one contiguous 1-KB load.
// ---------------------------------------------------------------------------
__global__ __launch_bounds__(256) void k_wpack(const float* __restrict__ w,
                                               unsigned short* __restrict__ wp) {
  int idx = blockIdx.x * 256 + threadIdx.x;   // 0..16383
  int lane = idx & 63;
  int n = (idx >> 6) & 7;
  int ks = idx >> 9;                          // 0..31
  int fr = lane & 15, kg = lane >> 4;
  const float* src = w + (size_t)(n * 16 + fr) * NODE_DIM + ks * 32 + kg * 8;
  float4 v0 = *(const float4*)(src);
  float4 v1 = *(const float4*)(src + 4);
  unsigned int* o = (unsigned int*)(wp + (size_t)idx * 8);
  o[0] = pkbf(v0.x, v0.y);
  o[1] = pkbf(v0.z, v0.w);
  o[2] = pkbf(v1.x, v1.y);
  o[3] = pkbf(v1.z, v1.w);
}

// ---------------------------------------------------------------------------
// K1: h = bf16(relu(x @ proj_w^T + proj_b))
// R4: BARRIER-FREE. R0-R2 all shared the LDS + 2-barrier-per-K-step
// structure whose vmcnt(0)+s_barrier drain serialized the HBM stream to
// ~1.7 TB/s regardless of coalescing/occupancy fixes. Now: no LDS, no
// __syncthreads. Each wave owns a 32-row strip; A-frags read directly from
// x (wave instr = 16 rows x full 128B lines), cvt in-register; B-frags
// read from the fragment-packed bf16 weights (1KB contiguous per read,
// L2-resident). A-loads pipelined 1 K-step ahead with static reg names.
// ---------------------------------------------------------------------------
__global__ __launch_bounds__(256, 3) void k_proj(const float* __restrict__ x,
                                                 const unsigned short* __restrict__ wp,
                                                 const float* __restrict__ pb,
                                                 unsigned short* __restrict__ h) {
  const int wave = threadIdx.x >> 6, lane = threadIdx.x & 63;
  const int fr = lane & 15, kg = lane >> 4;
  const int strip = blockIdx.x * 4 + wave;    // 0..1567
  const int m0 = strip * 32;

  int r0 = m0 + fr;      if (r0 >= N_NODES) r0 = N_NODES - 1;  // clamp: rows
  int r1 = m0 + 16 + fr; if (r1 >= N_NODES) r1 = N_NODES - 1;  // >=N unused
  const float* a0p = x + (size_t)r0 * NODE_DIM + kg * 8;
  const float* a1p = x + (size_t)r1 * NODE_DIM + kg * 8;
  const bf16x8* bp = (const bf16x8*)wp + lane;   // + (ks*8+n)*64

  f32x4 acc[2][8] = {};

  float4 xa0, xa1, xa2, xa3;   // A set X
  float4 ya0, ya1, ya2, ya3;   // A set Y

#define LOADA_X(KS) { const float* p0 = a0p + (KS) * 32; const float* p1 = a1p + (KS) * 32; \
  xa0 = *(const float4*)p0; xa1 = *(const float4*)(p0 + 4); \
  xa2 = *(const float4*)p1; xa3 = *(const float4*)(p1 + 4); }
#define LOADA_Y(KS) { const float* p0 = a0p + (KS) * 32; const float* p1 = a1p + (KS) * 32; \
  ya0 = *(const float4*)p0; ya1 = *(const float4*)(p0 + 4); \
  ya2 = *(const float4*)p1; ya3 = *(const float4*)(p1 + 4); }

#define COMPUTE(A0, A1, A2, A3, KS) { \
  bf16x8 bfv[8]; \
  _Pragma("unroll") \
  for (int n = 0; n < 8; n++) bfv[n] = bp[((KS) * 8 + n) * 64]; \
  u32x4 pa0, pa1; \
  pa0[0] = pkbf(A0.x, A0.y); pa0[1] = pkbf(A0.z, A0.w); \
  pa0[2] = pkbf(A1.x, A1.y); pa0[3] = pkbf(A1.z, A1.w); \
  pa1[0] = pkbf(A2.x, A2.y); pa1[1] = pkbf(A2.z, A2.w); \
  pa1[2] = pkbf(A3.x, A3.y); pa1[3] = pkbf(A3.z, A3.w); \
  bf16x8 af0 = __builtin_bit_cast(bf16x8, pa0); \
  bf16x8 af1 = __builtin_bit_cast(bf16x8, pa1); \
  _Pragma("unroll") \
  for (int n = 0; n < 8; n++) { \
    acc[0][n] = __builtin_amdgcn_mfma_f32_16x16x32_bf16(af0, bfv[n], acc[0][n], 0, 0, 0); \
    acc[1][n] = __builtin_amdgcn_mfma_f32_16x16x32_bf16(af1, bfv[n], acc[1][n], 0, 0, 0); \
  } }

  LOADA_X(0);
  for (int ks = 0; ks < 32; ks += 2) {
    LOADA_Y(ks + 1);
    COMPUTE(xa0, xa1, xa2, xa3, ks);
    if (ks + 2 < 32) LOADA_X(ks + 2);
    COMPUTE(ya0, ya1, ya2, ya3, ks + 1);
  }
#undef LOADA_X
#undef LOADA_Y
#undef COMPUTE

  const int cr = (lane >> 4) * 4, cc = lane & 15;
#pragma unroll
  for (int n = 0; n < 8; n++) {
    const int col = n * 16 + cc;
    const float bias = pb[col];
#pragma unroll
    for (int m = 0; m < 2; m++) {
      const int rowb = m0 + m * 16 + cr;
#pragma unroll
      for (int i = 0; i < 4; i++) {
        float v = acc[m][n][i] + bias;
        // rows >= N_NODES land in the PAD region of h and are never read
        h[(size_t)(rowb + i) * HID + col] = f2bf(v > 0.f ? v : 0.f);
      }
    }
  }
}

// ---------------------------------------------------------------------------
// CSR build: hist -> scan -> scan -> scatter(packed) -> per-bucket CSR
// ---------------------------------------------------------------------------
__global__ __launch_bounds__(256) void k_hist(const int* __restrict__ ei,
                                              int* __restrict__ counts) {
  __shared__ int bins[NBUCK];
  int t = threadIdx.x;
  if (t < NBUCK) bins[t] = 0;
  __syncthreads();
  int base = blockIdx.x * SHARD;
  for (int i = t; i < SHARD; i += 256)
    atomicAdd(&bins[ei[N_EDGES + base + i] >> 8], 1);
  __syncthreads();
  if (t < NBUCK) counts[t * 256 + blockIdx.x] = bins[t];
}

__global__ __launch_bounds__(256) void k_s1(const int* __restrict__ counts,
                                            int* __restrict__ basem,
                                            int* __restrict__ btot) {
  __shared__ int buf[2][256];
  int t = threadIdx.x, b = blockIdx.x;
  int v = counts[b * 256 + t];
  int excl = scan256_excl(v, buf, t);
  basem[b * 256 + t] = excl;
  if (t == 255) btot[b] = excl + v;
}

__global__ __launch_bounds__(256) void k_s2(const int* __restrict__ btot,
                                            int* __restrict__ bstart,
                                            float* __restrict__ accum) {
  __shared__ int buf[2][256];
  int t = threadIdx.x;
  int v = (t < NBUCK) ? btot[t] : 0;
  int excl = scan256_excl(v, buf, t);
  if (t < NBUCK) bstart[t] = excl;
  if (t == 0) bstart[NBUCK] = N_EDGES;
  if (t < HID) accum[t] = 0.f;
}

__global__ __launch_bounds__(256) void k_scatter(const int* __restrict__ ei,
                                                 const int* __restrict__ basem,
                                                 const int* __restrict__ bstart,
                                                 unsigned int* __restrict__ bs) {
  __shared__ int cur[NBUCK];
  int t = threadIdx.x;
  if (t < NBUCK) cur[t] = bstart[t] + basem[t * 256 + blockIdx.x];
  __syncthreads();
  int base = blockIdx.x * SHARD;
  for (int i = t; i < SHARD; i += 256) {
    int e = base + i;
    unsigned int src = (unsigned int)ei[e];
    unsigned int dst = (unsigned int)ei[N_EDGES + e];
    int pos = atomicAdd(&cur[dst >> 8], 1);
    bs[pos] = src | ((dst & 255u) << 16);
  }
}

// per-bucket exact CSR (LDS atomics on 1 cursor/edge only); nbr as u16
__global__ __launch_bounds__(256) void k_bucket(const int* __restrict__ bstart,
                                                const unsigned int* __restrict__ bs,
                                                unsigned short* __restrict__ nbr,
                                                int* __restrict__ offs,
                                                int* __restrict__ deg) {
  __shared__ int bins[256];
  __shared__ int buf[2][256];
  __shared__ int curs[256];
  int t = threadIdx.x, b = blockIdx.x;
  int s = bstart[b], e = bstart[b + 1];
  bins[t] = 0;
  __syncthreads();
  for (int i = s + t; i < e; i += 256)
    atomicAdd(&bins[(bs[i] >> 16) & 255u], 1);
  __syncthreads();
  int v = bins[t];
  int excl = scan256_excl(v, buf, t);
  int node = b * 256 + t;
  deg[node]  = v;
  offs[node] = s + excl;
  curs[t]    = s + excl;
  __syncthreads();
  for (int i = s + t; i < e; i += 256) {
    unsigned int p = bs[i];
    int pos = atomicAdd(&curs[(p >> 16) & 255u], 1);
    nbr[pos] = (unsigned short)(p & 0xffffu);
  }
}

// ---------------------------------------------------------------------------
// K_GATHER: mean over neighbors. One wave/node; 4 groups x 16 lanes x 16B;
// 2x unroll -> 8 row-loads in flight per wave.
// ---------------------------------------------------------------------------
__global__ __launch_bounds__(256) void k_gather(const unsigned short* __restrict__ h,
                                                const unsigned short* __restrict__ nbr,
                                                const int* __restrict__ offs,
                                                const int* __restrict__ deg,
                                                unsigned short* __restrict__ mn) {
  const int wave = threadIdx.x >> 6;
  const int lane = threadIdx.x & 63;
  const int node = blockIdx.x * 4 + wave;
  if (node >= N_NODES) return;
  const int g = lane >> 4, li = lane & 15;
  const int d  = deg[node];
  const int st = offs[node];
  float a[8] = {0.f, 0.f, 0.f, 0.f, 0.f, 0.f, 0.f, 0.f};
  int n = g;
  for (; n + 4 < d; n += 8) {
    int s0 = nbr[st + n];
    int s1 = nbr[st + n + 4];
    u16x8 v0 = *(const u16x8*)(h + (size_t)s0 * HID + li * 8);
    u16x8 v1 = *(const u16x8*)(h + (size_t)s1 * HID + li * 8);
#pragma unroll
    for (int k = 0; k < 8; k++) a[k] += bf2f(v0[k]) + bf2f(v1[k]);
  }
  if (n < d) {
    int s0 = nbr[st + n];
    u16x8 v0 = *(const u16x8*)(h + (size_t)s0 * HID + li * 8);
#pragma unroll
    for (int k = 0; k < 8; k++) a[k] += bf2f(v0[k]);
  }
#pragma unroll
  for (int k = 0; k < 8; k++) {
    a[k] += __shfl_xor(a[k], 16);
    a[k] += __shfl_xor(a[k], 32);
  }
  if (g == 0) {
    float inv = 1.f / fmaxf((float)d, 1.f);
    u16x8 r;
#pragma unroll
    for (int k = 0; k < 8; k++) r[k] = f2bf(a[k] * inv);
    *(u16x8*)(mn + (size_t)node * HID + li * 8) = r;
  }
}

// ---------------------------------------------------------------------------
// K_SAGE: h2 = [mn|h] @ [wl|wr]^T + lb, fused LayerNorm+ReLU+mean-pool.
// h2 never hits global memory.
// ---------------------------------------------------------------------------
__global__ __launch_bounds__(256) void k_sage(const unsigned short* __restrict__ mn,
                                              const unsigned short* __restrict__ h,
                                              const float* __restrict__ wl,
                                              const float* __restrict__ wr,
                                              const float* __restrict__ lb,
                                              const float* __restrict__ lg,
                                              const float* __restrict__ lbt,
                                              float* __restrict__ accum) {
  __shared__ unsigned short As[128 * 32];
  __shared__ unsigned short Bs[128 * 32];
  __shared__ float T3[32 * 128];
  __shared__ float red[4][128];
  const int tid = threadIdx.x;
  const int m0 = blockIdx.x * 128;
  const int wave = tid >> 6, lane = tid & 63;
  const int wm = (wave >> 1) * 64, wn = (wave & 1) * 64;
  const int srow = tid >> 1, scol = (tid & 1) * 16;
  const int fr = lane & 15, ko = (lane >> 4) * 8;

  f32x4 acc[4][4] = {};

  for (int k0 = 0; k0 < 2 * HID; k0 += 32) {
    const unsigned short* baseA = (k0 < HID) ? mn : h;
    const float* baseB = (k0 < HID) ? wl : wr;
    const int kk = (k0 & (HID - 1)) + scol;
    const int arow = m0 + srow;
    u16x8 a0 = {0, 0, 0, 0, 0, 0, 0, 0}, a1 = a0;
    if (arow < N_NODES) {
      const u16x8* p = (const u16x8*)(baseA + (size_t)arow * HID + kk);
      a0 = p[0]; a1 = p[1];
    }
    const float4* q = (const float4*)(baseB + (size_t)srow * HID + kk);
    float4 b0 = q[0], b1 = q[1], b2 = q[2], b3 = q[3];

    __syncthreads();
    *(u16x8*)&As[srow * 32 + scol]     = a0;
    *(u16x8*)&As[srow * 32 + scol + 8] = a1;
    unsigned int* db = (unsigned int*)&Bs[srow * 32 + scol];
    db[0] = pkbf(b0.x, b0.y); db[1] = pkbf(b0.z, b0.w);
    db[2] = pkbf(b1.x, b1.y); db[3] = pkbf(b1.z, b1.w);
    db[4] = pkbf(b2.x, b2.y); db[5] = pkbf(b2.z, b2.w);
    db[6] = pkbf(b3.x, b3.y); db[7] = pkbf(b3.z, b3.w);
    __syncthreads();

    bf16x8 af[4], bfr[4];
#pragma unroll
    for (int m = 0; m < 4; m++)
      af[m] = *(const bf16x8*)&As[(wm + m * 16 + fr) * 32 + ko];
#pragma unroll
    for (int n = 0; n < 4; n++)
      bfr[n] = *(const bf16x8*)&Bs[(wn + n * 16 + fr) * 32 + ko];
#pragma unroll
    for (int m = 0; m < 4; m++)
#pragma unroll
      for (int n = 0; n < 4; n++)
        acc[m][n] = __builtin_amdgcn_mfma_f32_16x16x32_bf16(af[m], bfr[n], acc[m][n], 0, 0, 0);
  }

  const int cr = (lane >> 4) * 4, cc = lane & 15;
  const int p = wave >> 1;
  const float g0 = lg[lane], g1 = lg[lane + 64];
  const float t0 = lbt[lane], t1 = lbt[lane + 64];
  float ax = 0.f, ay = 0.f;
#pragma unroll
  for (int m = 0; m < 4; m++) {
    __syncthreads();
#pragma unroll
    for (int n = 0; n < 4; n++) {
      const int col = wn + n * 16 + cc;
      const float bias = lb[col];
#pragma unroll
      for (int i = 0; i < 4; i++)
        T3[(p * 16 + cr + i) * 128 + col] = acc[m][n][i] + bias;
    }
    __syncthreads();
    for (int r8 = 0; r8 < 8; r8++) {
      int q8 = wave * 8 + r8;
      int grow = m0 + (q8 >> 4) * 64 + m * 16 + (q8 & 15);
      float v0 = T3[q8 * 128 + lane];
      float v1 = T3[q8 * 128 + lane + 64];
      float sum = v0 + v1, ss = v0 * v0 + v1 * v1;
#pragma unroll
      for (int off = 32; off > 0; off >>= 1) {
        sum += __shfl_xor(sum, off);
        ss  += __shfl_xor(ss, off);
      }
      float mu  = sum * (1.f / HID);
      float var = ss * (1.f / HID) - mu * mu;
      float rinv = rsqrtf(var + LN_EPS);
      if (grow < N_NODES) {
        float y0 = (v0 - mu) * rinv * g0 + t0;
        float y1 = (v1 - mu) * rinv * g1 + t1;
        ax += fmaxf(y0, 0.f);
        ay += fmaxf(y1, 0.f);
      }
    }
  }
  red[wave][lane]      = ax;
  red[wave][lane + 64] = ay;
  __syncthreads();
  if (wave == 0) {
    float a  = red[0][lane] + red[1][lane] + red[2][lane] + red[3][lane];
    float bb = red[0][lane + 64] + red[1][lane + 64] + red[2][lane + 64] + red[3][lane + 64];
    atomicAdd(&accum[lane], a);
    atomicAdd(&accum[lane + 64], bb);
  }
}

// ---------------------------------------------------------------------------
__global__ __launch_bounds__(128) void k_final(const float* __restrict__ accum,
                                               const float* __restrict__ ow,
                                               const float* __restrict__ ob,
                                               float* __restrict__ out) {
  __shared__ float gs[HID];
  int t = threadIdx.x;
  gs[t] = accum[t] * (1.f / N_NODES);
  __syncthreads();
  float s = ob[t];
  for (int k = 0; k < HID; k++) s += gs[k] * ow[t * HID + k];
  out[t] = s;
}

// ---------------------------------------------------------------------------
extern "C" void kernel_launch(void* const* d_in, const int* in_sizes, int n_in,
                              void* d_out, int out_size, void* d_ws, size_t ws_size,
                              hipStream_t stream) {
  const float* x   = (const float*)d_in[0];
  const int*   ei  = (const int*)d_in[1];
  const float* pw  = (const float*)d_in[2];
  const float* pb  = (const float*)d_in[3];
  const float* wl  = (const float*)d_in[4];
  const float* lb  = (const float*)d_in[5];
  const float* wr  = (const float*)d_in[6];
  const float* lg  = (const float*)d_in[7];
  const float* lbt = (const float*)d_in[8];
  const float* ow  = (const float*)d_in[9];
  const float* ob  = (const float*)d_in[10];
  float* out = (float*)d_out;

  const int PAD = NBUCK * 256;  // 50176
  unsigned short* h  = (unsigned short*)d_ws;                   // PAD*128 bf16
  unsigned short* mn = h + (size_t)PAD * HID;                   // PAD*128 bf16
  unsigned int* bsp  = (unsigned int*)(mn + (size_t)PAD * HID); // E packed u32
  unsigned short* nbr = (unsigned short*)(bsp + N_EDGES);       // E u16
  int* counts = (int*)(nbr + N_EDGES);                          // NBUCK*256
  int* basem  = counts + NBUCK * 256;
  int* btot   = basem + NBUCK * 256;                            // 256
  int* bstart = btot + 256;                                     // 256
  int* offs   = bstart + 256;                                   // PAD
  int* deg    = offs + PAD;                                     // PAD
  float* accum = (float*)(deg + PAD);                           // 128
  unsigned short* wp = (unsigned short*)(accum + 128);          // HID*NODE_DIM bf16 (packed)

  const int MB  = (N_NODES + 127) / 128;  // 391 (k_sage)
  const int PB  = (N_NODES + 127) / 128;  // 392-strip grid: 1568 strips / 4 waves
  (void)PB;

  hipLaunchKernelGGL(k_wpack,   dim3(64),    dim3(256), 0, stream, pw, wp);
  hipLaunchKernelGGL(k_hist,    dim3(256),   dim3(256), 0, stream, ei, counts);
  hipLaunchKernelGGL(k_s1,      dim3(NBUCK), dim3(256), 0, stream, counts, basem, btot);
  hipLaunchKernelGGL(k_s2,      dim3(1),     dim3(256), 0, stream, btot, bstart, accum);
  hipLaunchKernelGGL(k_scatter, dim3(256),   dim3(256), 0, stream, ei, basem, bstart, bsp);
  hipLaunchKernelGGL(k_bucket,  dim3(NBUCK), dim3(256), 0, stream, bstart, bsp, nbr, offs, deg);
  hipLaunchKernelGGL(k_proj,    dim3(392),   dim3(256), 0, stream, x, wp, pb, h);
  hipLaunchKernelGGL(k_gather,  dim3((N_NODES + 3) / 4), dim3(256), 0, stream, h, nbr, offs, deg, mn);
  hipLaunchKernelGGL(k_sage,    dim3(MB),    dim3(256), 0, stream, mn, h, wl, wr, lb, lg, lbt, accum);
  hipLaunchKernelGGL(k_final,   dim3(1),     dim3(128), 0, stream, accum, ow, ob, out);
}